// Round 6
// baseline (266.336 us; speedup 1.0000x reference)
//
#include <hip/hip_runtime.h>
#include <hip/hip_bf16.h>
#include <stdint.h>

#define B_DIM 32
#define N_DIM 1024
#define F_DIM 128
#define ALPHA 0.2f
#define NROWS (B_DIM * N_DIM)        // 32768
#define TAIL_ROWS 128                // rows owned by the single tail block
#define MAIN_ROWS (NROWS - TAIL_ROWS)
#define SCORE_BYTES ((size_t)(2 * NROWS) * sizeof(float))  // 256 KiB

// clang-native vector types (HIP's float4/ushort4 are wrapper classes that
// __builtin_nontemporal_store rejects)
typedef float          vf4 __attribute__((ext_vector_type(4)));
typedef unsigned short vh4 __attribute__((ext_vector_type(4)));
typedef unsigned int   vu4 __attribute__((ext_vector_type(4)));

// f32 -> bf16 bits with hardware RNE, without relying on __hip_bfloat16
// internals (member name varies across ROCm versions).
__device__ __forceinline__ unsigned short f32_to_bf16_bits(float f) {
    union { __hip_bfloat16 h; unsigned short u; } cvt;
    cvt.h = __float2bfloat16(f);
    return cvt.u;
}

// adj[0,0,0] == 1.0 always (self-loop on the diagonal).
//   f32 buffer:  first 32-bit word == 0x3F800000
//   bf16 buffer: first 32-bit word == (elem1<<16) | 0x3F80  (low half != 0)
__device__ __forceinline__ bool probe_is_f32(const void* adj) {
    return *(const uint32_t*)adj == 0x3F800000u;
}

// Scores scratch = last 256 KiB of d_out (ws_size proved < 256 KiB in R2/R3).
// f32: overlaps last 64 output rows; bf16: last 128. TAIL_ROWS=128 covers both.
// Layout: [ s_src[NROWS] | s_dst[NROWS] ] as f32.
template <bool F32>
__device__ __forceinline__ float* score_base(void* out) {
    const size_t out_bytes = (size_t)NROWS * N_DIM * (F32 ? 4 : 2);
    return (float*)((char*)out + out_bytes - SCORE_BYTES);
}

// ---------------------------------------------------------------------------
// Kernel A: per-node scores. One wave per row, 2 features/lane, shuffle-reduce.
// Writes only the scratch region (tail of d_out).
// ---------------------------------------------------------------------------
template <bool F32>
__device__ __forceinline__ void scores_body(
    const void* __restrict__ feats_v, const void* __restrict__ a_v, void* out)
{
    float* base  = score_base<F32>(out);
    float* s_src = base;
    float* s_dst = base + NROWS;

    const int wid  = threadIdx.x >> 6;
    const int lane = threadIdx.x & 63;
    const int row  = blockIdx.x * 4 + wid;      // 0 .. NROWS-1
    const int f0   = lane * 2;

    float x0, x1, a10, a11, a20, a21;
    if (F32) {
        const float* fp = (const float*)feats_v + (size_t)row * F_DIM + f0;
        const float* ap = (const float*)a_v;
        x0 = fp[0]; x1 = fp[1];
        a10 = ap[f0];         a11 = ap[f0 + 1];
        a20 = ap[F_DIM + f0]; a21 = ap[F_DIM + f0 + 1];
    } else {
        const __hip_bfloat16* fp = (const __hip_bfloat16*)feats_v + (size_t)row * F_DIM + f0;
        const __hip_bfloat16* ap = (const __hip_bfloat16*)a_v;
        x0  = __bfloat162float(fp[0]);           x1  = __bfloat162float(fp[1]);
        a10 = __bfloat162float(ap[f0]);          a11 = __bfloat162float(ap[f0 + 1]);
        a20 = __bfloat162float(ap[F_DIM + f0]);  a21 = __bfloat162float(ap[F_DIM + f0 + 1]);
    }

    float v1 = x0 * a10 + x1 * a11;
    float v2 = x0 * a20 + x1 * a21;
    #pragma unroll
    for (int off = 32; off > 0; off >>= 1) {
        v1 += __shfl_down(v1, off, 64);
        v2 += __shfl_down(v2, off, 64);
    }
    if (lane == 0) { s_src[row] = v1; s_dst[row] = v2; }
}

__global__ __launch_bounds__(256) void scores_kernel(
    const void* __restrict__ adj, const void* __restrict__ feats,
    const void* __restrict__ a, void* out)
{
    if (probe_is_f32(adj)) scores_body<true>(feats, a, out);
    else                   scores_body<false>(feats, a, out);
}

// ---------------------------------------------------------------------------
// Wave-level softmax for one row. Lane owns 16 j's as 4 chunks of 4
// (j = c*256 + lane*4 + k). No barriers, no LDS.
// ---------------------------------------------------------------------------
template <bool F32>
__device__ __forceinline__ void wave_softmax_row(
    const void* __restrict__ adj_v, void* __restrict__ out_v,
    int row, float ssrc, const float* __restrict__ sdst /* 1024 floats */)
{
    const int lane = threadIdx.x & 63;

    float p[16];
    uint32_t vmask = 0;
    float lmax = -1e30f;

    #pragma unroll
    for (int c = 0; c < 4; ++c) {
        const int idx = c * 64 + lane;          // vec4 index within row
        const vf4 sd = ((const vf4*)sdst)[idx];
        bool v[4];
        if (F32) {
            const vu4 av = ((const vu4*)((const float*)adj_v + (size_t)row * N_DIM))[idx];
            v[0] = av.x != 0u; v[1] = av.y != 0u; v[2] = av.z != 0u; v[3] = av.w != 0u;
        } else {
            const vh4 av = ((const vh4*)((const __hip_bfloat16*)adj_v + (size_t)row * N_DIM))[idx];
            v[0] = av.x != 0; v[1] = av.y != 0; v[2] = av.z != 0; v[3] = av.w != 0;
        }
        const float sdk[4] = {sd.x, sd.y, sd.z, sd.w};
        #pragma unroll
        for (int k = 0; k < 4; ++k) {
            float t = ssrc + sdk[k];
            t = (t >= 0.0f) ? t : ALPHA * t;    // LeakyReLU
            p[c * 4 + k] = t;
            if (v[k]) { lmax = fmaxf(lmax, t); vmask |= 1u << (c * 4 + k); }
        }
    }

    // wave butterfly max — every lane ends with the row max
    #pragma unroll
    for (int off = 1; off < 64; off <<= 1)
        lmax = fmaxf(lmax, __shfl_xor(lmax, off, 64));

    float lsum = 0.0f;
    #pragma unroll
    for (int i = 0; i < 16; ++i) {
        p[i] = (vmask >> i) & 1 ? __expf(p[i] - lmax) : 0.0f;
        lsum += p[i];
    }
    #pragma unroll
    for (int off = 1; off < 64; off <<= 1)
        lsum += __shfl_xor(lsum, off, 64);
    const float inv = 1.0f / lsum;              // >=1 edge per row (self-loop)

    #pragma unroll
    for (int c = 0; c < 4; ++c) {
        const int idx = c * 64 + lane;
        if (F32) {
            vf4 o;
            o.x = p[c*4+0] * inv; o.y = p[c*4+1] * inv;
            o.z = p[c*4+2] * inv; o.w = p[c*4+3] * inv;
            __builtin_nontemporal_store(o,
                ((vf4*)((float*)out_v + (size_t)row * N_DIM)) + idx);
        } else {
            vh4 o;
            o.x = f32_to_bf16_bits(p[c*4+0] * inv);
            o.y = f32_to_bf16_bits(p[c*4+1] * inv);
            o.z = f32_to_bf16_bits(p[c*4+2] * inv);
            o.w = f32_to_bf16_bits(p[c*4+3] * inv);
            __builtin_nontemporal_store(o,
                ((vh4*)((__hip_bfloat16*)out_v + (size_t)row * N_DIM)) + idx);
        }
    }
}

// ---------------------------------------------------------------------------
// Kernel B: main rows 0 .. MAIN_ROWS-1. One wave per row; reads scores from
// the scratch (never writes it).
// ---------------------------------------------------------------------------
template <bool F32>
__device__ __forceinline__ void main_body(const void* __restrict__ adj_v, void* out_v)
{
    const int wid = threadIdx.x >> 6;
    const int row = blockIdx.x * 4 + wid;       // 0 .. MAIN_ROWS-1
    const int b   = row >> 10;

    const float* base = score_base<F32>(out_v);
    const float  ssrc = base[row];              // wave-uniform
    const float* sdst = base + NROWS + (size_t)b * N_DIM;

    wave_softmax_row<F32>(adj_v, out_v, row, ssrc, sdst);
}

__global__ __launch_bounds__(256) void main_kernel(
    const void* __restrict__ adj, void* out)
{
    if (probe_is_f32(adj)) main_body<true>(adj, out);
    else                   main_body<false>(adj, out);
}

// ---------------------------------------------------------------------------
// Kernel C: ONE block, 1024 threads (16 waves), owns the last TAIL_ROWS rows
// (the region containing the scratch). Stages all needed scores into LDS
// behind a single barrier, then overwrites freely. 8 rows per wave.
// ---------------------------------------------------------------------------
template <bool F32>
__device__ __forceinline__ void tail_body(const void* __restrict__ adj_v, void* out_v)
{
    __shared__ float sdst_sh[N_DIM];            // s_dst[31, :]
    __shared__ float ssrc_sh[TAIL_ROWS];        // s_src[last 128 rows]

    const int tid  = threadIdx.x;
    const float* base = score_base<F32>(out_v);

    sdst_sh[tid] = base[NROWS + (B_DIM - 1) * N_DIM + tid];
    if (tid < TAIL_ROWS) ssrc_sh[tid] = base[MAIN_ROWS + tid];
    __syncthreads();

    const int wid = tid >> 6;                   // 0..15
    #pragma unroll
    for (int r = 0; r < TAIL_ROWS / 16; ++r) {  // 8 rows per wave
        const int rr  = wid * (TAIL_ROWS / 16) + r;
        const int row = MAIN_ROWS + rr;
        wave_softmax_row<F32>(adj_v, out_v, row, ssrc_sh[rr], sdst_sh);
    }
}

__global__ __launch_bounds__(1024) void tail_kernel(
    const void* __restrict__ adj, void* out)
{
    if (probe_is_f32(adj)) tail_body<true>(adj, out);
    else                   tail_body<false>(adj, out);
}

extern "C" void kernel_launch(void* const* d_in, const int* in_sizes, int n_in,
                              void* d_out, int out_size, void* d_ws, size_t ws_size,
                              hipStream_t stream) {
    const void* adj   = d_in[0];   // [B,N,N]
    const void* feats = d_in[1];   // [B,N,F]
    const void* a     = d_in[2];   // [2F,1]
    (void)d_ws; (void)ws_size;     // ws proved too small (R2); scratch lives in d_out tail

    scores_kernel<<<NROWS / 4, 256, 0, stream>>>(adj, feats, a, d_out);
    main_kernel<<<MAIN_ROWS / 4, 256, 0, stream>>>(adj, d_out);
    tail_kernel<<<1, 1024, 0, stream>>>(adj, d_out);
}

// Round 7
// 262.162 us; speedup vs baseline: 1.0159x; 1.0159x over previous
//
#include <hip/hip_runtime.h>
#include <hip/hip_bf16.h>
#include <stdint.h>

#define B_DIM 32
#define N_DIM 1024
#define F_DIM 128
#define ALPHA 0.2f
#define NROWS (B_DIM * N_DIM)        // 32768
#define TAIL_ROWS 128                // last rows, recomputed (covers f32 & bf16 scratch overlap)
#define MAIN_ROWS (NROWS - TAIL_ROWS)
#define SCORE_BYTES ((size_t)(2 * NROWS) * sizeof(float))  // 256 KiB

// clang-native vector types
typedef float          vf4 __attribute__((ext_vector_type(4)));
typedef unsigned short vh4 __attribute__((ext_vector_type(4)));
typedef unsigned int   vu4 __attribute__((ext_vector_type(4)));

__device__ __forceinline__ unsigned short f32_to_bf16_bits(float f) {
    union { __hip_bfloat16 h; unsigned short u; } cvt;
    cvt.h = __float2bfloat16(f);
    return cvt.u;
}

// adj[0,0,0] == 1.0 always (self-loop). f32 word = 0x3F800000 exactly.
// (R6 FETCH_SIZE = 32640 rows x 4 KB confirmed the F32 branch is taken.)
__device__ __forceinline__ bool probe_is_f32(const void* adj) {
    return *(const uint32_t*)adj == 0x3F800000u;
}

// Scores scratch = last 256 KiB of d_out (d_ws proved unsafe in R2).
// Layout: [ s_src[NROWS] | s_dst[NROWS] ] f32.
template <bool F32>
__device__ __forceinline__ float* score_base(void* out) {
    const size_t out_bytes = (size_t)NROWS * N_DIM * (F32 ? 4 : 2);
    return (float*)((char*)out + out_bytes - SCORE_BYTES);
}

// ---------------------------------------------------------------------------
// Kernel A: per-node scores. One wave per row, 2 features/lane, shuffle-reduce.
// ---------------------------------------------------------------------------
template <bool F32>
__device__ __forceinline__ void scores_body(
    const void* __restrict__ feats_v, const void* __restrict__ a_v, void* out)
{
    float* base  = score_base<F32>(out);
    float* s_src = base;
    float* s_dst = base + NROWS;

    const int wid  = threadIdx.x >> 6;
    const int lane = threadIdx.x & 63;
    const int row  = blockIdx.x * 4 + wid;
    const int f0   = lane * 2;

    float x0, x1, a10, a11, a20, a21;
    if (F32) {
        const float* fp = (const float*)feats_v + (size_t)row * F_DIM + f0;
        const float* ap = (const float*)a_v;
        x0 = fp[0]; x1 = fp[1];
        a10 = ap[f0];         a11 = ap[f0 + 1];
        a20 = ap[F_DIM + f0]; a21 = ap[F_DIM + f0 + 1];
    } else {
        const __hip_bfloat16* fp = (const __hip_bfloat16*)feats_v + (size_t)row * F_DIM + f0;
        const __hip_bfloat16* ap = (const __hip_bfloat16*)a_v;
        x0  = __bfloat162float(fp[0]);           x1  = __bfloat162float(fp[1]);
        a10 = __bfloat162float(ap[f0]);          a11 = __bfloat162float(ap[f0 + 1]);
        a20 = __bfloat162float(ap[F_DIM + f0]);  a21 = __bfloat162float(ap[F_DIM + f0 + 1]);
    }

    float v1 = x0 * a10 + x1 * a11;
    float v2 = x0 * a20 + x1 * a21;
    #pragma unroll
    for (int off = 32; off > 0; off >>= 1) {
        v1 += __shfl_down(v1, off, 64);
        v2 += __shfl_down(v2, off, 64);
    }
    if (lane == 0) { s_src[row] = v1; s_dst[row] = v2; }
}

__global__ __launch_bounds__(256) void scores_kernel(
    const void* __restrict__ adj, const void* __restrict__ feats,
    const void* __restrict__ a, void* out)
{
    if (probe_is_f32(adj)) scores_body<true>(feats, a, out);
    else                   scores_body<false>(feats, a, out);
}

// ---------------------------------------------------------------------------
// Wave-level masked softmax for one row. Lane owns 16 j's as 4 vec4 chunks.
// No barriers. Regular (L2 write-back) stores — nontemporal measured slower
// (R6: 3.37 TB/s vs fill's 6.78 TB/s on the same chip).
// ---------------------------------------------------------------------------
template <bool F32>
__device__ __forceinline__ void wave_softmax_row(
    const void* __restrict__ adj_v, void* __restrict__ out_v,
    int row, float ssrc, const float* __restrict__ sdst /* 1024 f32 */)
{
    const int lane = threadIdx.x & 63;

    float p[16];
    uint32_t vmask = 0;
    float lmax = -1e30f;

    #pragma unroll
    for (int c = 0; c < 4; ++c) {
        const int idx = c * 64 + lane;
        const vf4 sd = ((const vf4*)sdst)[idx];
        bool v[4];
        if (F32) {
            const vu4 av = ((const vu4*)((const float*)adj_v + (size_t)row * N_DIM))[idx];
            v[0] = av.x != 0u; v[1] = av.y != 0u; v[2] = av.z != 0u; v[3] = av.w != 0u;
        } else {
            const vh4 av = ((const vh4*)((const __hip_bfloat16*)adj_v + (size_t)row * N_DIM))[idx];
            v[0] = av.x != 0; v[1] = av.y != 0; v[2] = av.z != 0; v[3] = av.w != 0;
        }
        const float sdk[4] = {sd.x, sd.y, sd.z, sd.w};
        #pragma unroll
        for (int k = 0; k < 4; ++k) {
            float t = ssrc + sdk[k];
            t = (t >= 0.0f) ? t : ALPHA * t;
            p[c * 4 + k] = t;
            if (v[k]) { lmax = fmaxf(lmax, t); vmask |= 1u << (c * 4 + k); }
        }
    }

    #pragma unroll
    for (int off = 1; off < 64; off <<= 1)
        lmax = fmaxf(lmax, __shfl_xor(lmax, off, 64));

    float lsum = 0.0f;
    #pragma unroll
    for (int i = 0; i < 16; ++i) {
        p[i] = (vmask >> i) & 1 ? __expf(p[i] - lmax) : 0.0f;
        lsum += p[i];
    }
    #pragma unroll
    for (int off = 1; off < 64; off <<= 1)
        lsum += __shfl_xor(lsum, off, 64);
    const float inv = 1.0f / lsum;   // >=1 edge per row (self-loop)

    #pragma unroll
    for (int c = 0; c < 4; ++c) {
        const int idx = c * 64 + lane;
        if (F32) {
            vf4 o;
            o.x = p[c*4+0] * inv; o.y = p[c*4+1] * inv;
            o.z = p[c*4+2] * inv; o.w = p[c*4+3] * inv;
            ((vf4*)((float*)out_v + (size_t)row * N_DIM))[idx] = o;
        } else {
            vh4 o;
            o.x = f32_to_bf16_bits(p[c*4+0] * inv);
            o.y = f32_to_bf16_bits(p[c*4+1] * inv);
            o.z = f32_to_bf16_bits(p[c*4+2] * inv);
            o.w = f32_to_bf16_bits(p[c*4+3] * inv);
            ((vh4*)((__hip_bfloat16*)out_v + (size_t)row * N_DIM))[idx] = o;
        }
    }
}

// ---------------------------------------------------------------------------
// Kernel B: main rows 0 .. MAIN_ROWS-1, wave per row, reads scratch scores.
// ---------------------------------------------------------------------------
template <bool F32>
__device__ __forceinline__ void main_body(const void* __restrict__ adj_v, void* out_v)
{
    const int wid = threadIdx.x >> 6;
    const int row = blockIdx.x * 4 + wid;
    const int b   = row >> 10;

    const float* base = score_base<F32>(out_v);
    const float  ssrc = base[row];
    const float* sdst = base + NROWS + (size_t)b * N_DIM;

    wave_softmax_row<F32>(adj_v, out_v, row, ssrc, sdst);
}

__global__ __launch_bounds__(256) void main_kernel(
    const void* __restrict__ adj, void* out)
{
    if (probe_is_f32(adj)) main_body<true>(adj, out);
    else                   main_body<false>(adj, out);
}

// ---------------------------------------------------------------------------
// Kernel C: last TAIL_ROWS rows — 32 parallel blocks, 4 rows each (one per
// wave). Recomputes all needed scores from feats (no scratch dependence, so
// blocks may overwrite the scratch region in any order). sdst[31,:] built
// cooperatively into LDS with vectorized dots; ssrc per-wave via shuffle.
// ---------------------------------------------------------------------------
template <bool F32>
__device__ __forceinline__ void tail_body(
    const void* __restrict__ adj_v, const void* __restrict__ feats_v,
    const void* __restrict__ a_v, void* __restrict__ out_v)
{
    __shared__ float sdst_sh[N_DIM];

    const int tid  = threadIdx.x;
    const int wid  = tid >> 6;
    const int lane = tid & 63;
    const int b    = B_DIM - 1;                       // all tail rows in batch 31
    const int row  = MAIN_ROWS + blockIdx.x * 4 + wid;

    // sdst[31, j] for j = 4*tid .. 4*tid+3 (vectorized 128-length dots)
    #pragma unroll
    for (int k = 0; k < 4; ++k) {
        const int j = tid * 4 + k;
        float acc = 0.0f;
        if (F32) {
            const vf4* fp = (const vf4*)((const float*)feats_v + ((size_t)b * N_DIM + j) * F_DIM);
            const vf4* ap = (const vf4*)((const float*)a_v + F_DIM);
            #pragma unroll 8
            for (int f = 0; f < F_DIM / 4; ++f) {
                const vf4 x = fp[f], w = ap[f];
                acc += x.x * w.x + x.y * w.y + x.z * w.z + x.w * w.w;
            }
        } else {
            const __hip_bfloat16* fp = (const __hip_bfloat16*)feats_v + ((size_t)b * N_DIM + j) * F_DIM;
            const __hip_bfloat16* ap = (const __hip_bfloat16*)a_v + F_DIM;
            #pragma unroll 8
            for (int f = 0; f < F_DIM; ++f)
                acc += __bfloat162float(fp[f]) * __bfloat162float(ap[f]);
        }
        sdst_sh[j] = acc;
    }

    // ssrc for this wave's row: 2 features/lane + shuffle reduce + broadcast
    float ssrc;
    {
        const int f0 = lane * 2;
        float x0, x1, a0, a1;
        if (F32) {
            const float* fp = (const float*)feats_v + (size_t)row * F_DIM + f0;
            const float* ap = (const float*)a_v;
            x0 = fp[0]; x1 = fp[1]; a0 = ap[f0]; a1 = ap[f0 + 1];
        } else {
            const __hip_bfloat16* fp = (const __hip_bfloat16*)feats_v + (size_t)row * F_DIM + f0;
            const __hip_bfloat16* ap = (const __hip_bfloat16*)a_v;
            x0 = __bfloat162float(fp[0]); x1 = __bfloat162float(fp[1]);
            a0 = __bfloat162float(ap[f0]); a1 = __bfloat162float(ap[f0 + 1]);
        }
        float v = x0 * a0 + x1 * a1;
        #pragma unroll
        for (int off = 32; off > 0; off >>= 1)
            v += __shfl_down(v, off, 64);
        ssrc = __shfl(v, 0, 64);
    }
    __syncthreads();

    wave_softmax_row<F32>(adj_v, out_v, row, ssrc, sdst_sh);
}

__global__ __launch_bounds__(256) void tail_kernel(
    const void* __restrict__ adj, const void* __restrict__ feats,
    const void* __restrict__ a, void* __restrict__ out)
{
    if (probe_is_f32(adj)) tail_body<true>(adj, feats, a, out);
    else                   tail_body<false>(adj, feats, a, out);
}

extern "C" void kernel_launch(void* const* d_in, const int* in_sizes, int n_in,
                              void* d_out, int out_size, void* d_ws, size_t ws_size,
                              hipStream_t stream) {
    const void* adj   = d_in[0];   // [B,N,N]
    const void* feats = d_in[1];   // [B,N,F]
    const void* a     = d_in[2];   // [2F,1]
    (void)d_ws; (void)ws_size;     // scratch lives in d_out tail (proven safe R3/R6)

    scores_kernel<<<NROWS / 4, 256, 0, stream>>>(adj, feats, a, d_out);
    main_kernel<<<MAIN_ROWS / 4, 256, 0, stream>>>(adj, d_out);
    tail_kernel<<<TAIL_ROWS / 4, 256, 0, stream>>>(adj, feats, a, d_out);
}